// Round 6
// baseline (211.262 us; speedup 1.0000x reference)
//
#include <hip/hip_runtime.h>

// YOLOv1 loss: pred/label (16384, 30, 7, 7) fp32 -> scalar.
// R5: all prior rounds (direct loads, sync LDS, async dbuf LDS) pinned at
// ~73us / 2.6 TB/s with every pipe idle -> block lock-step phases starve HBM.
// New structure, zero barriers:
//   Path A (5/8 blocks): ch10-29 class term as pure elementwise stream
//       acc += label4 * (p-l)^2   (label4 is exactly 0.0/1.0)
//   Path B (3/8 blocks): ch0-9 IoU/coord/conf via wave-private LDS staging
//       (s_waitcnt lgkmcnt only, no __syncthreads; waves free-run)

#define NBATCH 16384
#define BSTRIDE 1470        // floats per record
#define BLOCK 256
#define GRID 2048
#define NA_BLOCKS 1280      // blockIdx%8 in {0..4}
#define NB_BLOCKS 768       // blockIdx%8 in {5,6,7}
#define N2 8028160          // 16384*490 float2-pairs in class region (ch10-29)

__device__ __forceinline__ float sq(float x) { return x * x; }

__global__ __launch_bounds__(BLOCK) void yolo_main(const float* __restrict__ pred,
                                                   const float* __restrict__ label,
                                                   float* __restrict__ partials) {
    __shared__ float lds[4][960];   // wave-private: [0,490) pred ch0-9, [496,938) label ch0-8
    __shared__ float smem[4];

    const int m = blockIdx.x & 7;
    const int g = blockIdx.x >> 3;
    const int tid = threadIdx.x;
    float acc = 0.0f;

    if (m < 5) {
        // ---------------- Path A: elementwise class term ----------------
        const int a_rank = g * 5 + m;                 // 0..1279
        const long long gstr = (long long)NA_BLOCKS * 1024;
        for (long long base = (long long)a_rank * 1024; base < N2; base += gstr) {
            // N2 % 1024 == 0 -> no per-element guard needed
#pragma unroll
            for (int j = 0; j < 4; ++j) {
                unsigned int i = (unsigned int)(base + j * 256 + tid);
                unsigned int rec = i / 490u;          // magic-mul
                unsigned int k = i - rec * 490u;      // float2 index in class region
                const float* rp = pred + (size_t)rec * BSTRIDE;
                const float* rl = label + (size_t)rec * BSTRIDE;
                float2 p2 = *(const float2*)(rp + 490 + 2 * k);
                float2 l2 = *(const float2*)(rl + 490 + 2 * k);
                unsigned int c0 = (2u * k) % 49u;     // cell of first elem (490%49==0)
                unsigned int c1 = (c0 == 48u) ? 0u : c0 + 1u;
                float w0 = rl[196 + c0];              // label ch4 (exactly 0.0 or 1.0)
                float w1 = rl[196 + c1];
                float d0 = p2.x - l2.x, d1 = p2.y - l2.y;
                acc += w0 * (d0 * d0) + w1 * (d1 * d1);
            }
        }
    } else {
        // ---------------- Path B: per-cell IoU/coord/conf ----------------
        const int b_rank = g * 3 + (m - 5);           // 0..767
        const int wave = tid >> 6, lane = tid & 63;
        float* ldsw = &lds[wave][0];
        float2* wp2 = (float2*)ldsw;                  // 245 float2: pred ch0-9
        float2* wl2 = (float2*)(ldsw + 496);          // 221 float2: label ch0-8
        const int wave_id = b_rank * 4 + wave;        // 0..3071

        const int cell = lane;                        // lanes 0..48 active in compute
        const int rr = cell / 7;
        const int cc = cell - rr * 7;
        const float fr = (float)rr, fc = (float)cc;
        const float inv7 = 1.0f / 7.0f;

        for (int rec = wave_id; rec < NBATCH; rec += NB_BLOCKS * 4) {
            const float2* gp = (const float2*)pred + (size_t)rec * 735;
            const float2* gl = (const float2*)label + (size_t)rec * 735;
#pragma unroll
            for (int r4 = 0; r4 < 4; ++r4) {
                int idx = r4 * 64 + lane;
                if (idx < 245) wp2[idx] = gp[idx];
                if (idx < 221) wl2[idx] = gl[idx];
            }
            // Wave-private LDS: drain DS writes so cross-lane reads are valid.
            asm volatile("s_waitcnt lgkmcnt(0)" ::: "memory");

            if (lane < 49) {
                float p[10], l[9];
#pragma unroll
                for (int ch = 0; ch < 10; ++ch) p[ch] = ldsw[ch * 49 + cell];
#pragma unroll
                for (int ch = 0; ch < 9; ++ch) l[ch] = ldsw[496 + ch * 49 + cell];

                float lcx = (l[0] + fc) * inv7;
                float lcy = (l[1] + fr) * inv7;
                float lhw = l[2] * 0.5f, lhh = l[3] * 0.5f;
                float lx1 = lcx - lhw, ly1 = lcy - lhh;
                float lx2 = lcx + lhw, ly2 = lcy + lhh;
                float larea = (lx2 - lx1) * (ly2 - ly1);

                float cx1 = (p[0] + fc) * inv7, cy1 = (p[1] + fr) * inv7;
                float x11 = cx1 - p[2] * 0.5f, y11 = cy1 - p[3] * 0.5f;
                float x12 = cx1 + p[2] * 0.5f, y12 = cy1 + p[3] * 0.5f;
                float iw1 = fmaxf(fminf(x12, lx2) - fmaxf(x11, lx1), 0.0f);
                float ih1 = fmaxf(fminf(y12, ly2) - fmaxf(y11, ly1), 0.0f);
                float int1 = iw1 * ih1;
                float a1 = (x12 - x11) * (y12 - y11);
                float iou1 = int1 / (a1 + larea - int1 + 1e-10f);

                float cx2 = (p[5] + fc) * inv7, cy2 = (p[6] + fr) * inv7;
                float x21 = cx2 - p[7] * 0.5f, y21 = cy2 - p[8] * 0.5f;
                float x22 = cx2 + p[7] * 0.5f, y22 = cy2 + p[8] * 0.5f;
                float iw2 = fmaxf(fminf(x22, lx2) - fmaxf(x21, lx1), 0.0f);
                float ih2 = fmaxf(fminf(y22, ly2) - fmaxf(y21, ly1), 0.0f);
                float int2 = iw2 * ih2;
                float a2 = (x22 - x21) * (y22 - y21);
                float iou2 = int2 / (a2 + larea - int2 + 1e-10f);

                bool ch1 = iou1 >= iou2;

                float coord1 = 5.0f * (sq(p[0] - l[0]) + sq(p[1] - l[1]))
                             + sq(sqrtf(p[2]) - sqrtf(l[2])) + sq(sqrtf(p[3]) - sqrtf(l[3]));
                float coord2 = 5.0f * (sq(p[5] - l[5]) + sq(p[6] - l[6]))
                             + sq(sqrtf(p[7]) - sqrtf(l[7])) + sq(sqrtf(p[8]) - sqrtf(l[8]));
                float obj1 = sq(p[4] - iou1);
                float obj2 = sq(p[9] - iou2);

                float obj_cell = (ch1 ? coord1 : coord2)
                               + (ch1 ? obj1 : obj2)
                               + 0.5f * (ch1 ? obj2 : obj1);   // class term lives in Path A
                float noobj_cell = 0.5f * sq(p[4] + p[9]);

                acc += (l[4] == 1.0f) ? obj_cell : noobj_cell;
            }
        }
    }

    // ---------------- Block reduce -> one partial per block ----------------
    float v = acc;
#pragma unroll
    for (int off = 32; off > 0; off >>= 1) v += __shfl_down(v, off, 64);

    const int lane = tid & 63;
    const int wave = tid >> 6;
    if (lane == 0) smem[wave] = v;
    __syncthreads();
    if (tid == 0) partials[blockIdx.x] = smem[0] + smem[1] + smem[2] + smem[3];
}

__global__ __launch_bounds__(BLOCK) void yolo_reduce(const float* __restrict__ partials,
                                                     float* __restrict__ out) {
    float s = 0.0f;
#pragma unroll
    for (int it = 0; it < GRID / BLOCK; ++it)   // 8 independent loads
        s += partials[it * BLOCK + threadIdx.x];

#pragma unroll
    for (int off = 32; off > 0; off >>= 1) s += __shfl_down(s, off, 64);

    __shared__ float smem[BLOCK / 64];
    const int lane = threadIdx.x & 63;
    const int wave = threadIdx.x >> 6;
    if (lane == 0) smem[wave] = s;
    __syncthreads();
    if (threadIdx.x == 0)
        out[0] = (smem[0] + smem[1] + smem[2] + smem[3]) * (1.0f / (float)NBATCH);
}

extern "C" void kernel_launch(void* const* d_in, const int* in_sizes, int n_in,
                              void* d_out, int out_size, void* d_ws, size_t ws_size,
                              hipStream_t stream) {
    const float* pred  = (const float*)d_in[0];
    const float* label = (const float*)d_in[1];
    float* out = (float*)d_out;
    float* partials = (float*)d_ws;   // GRID floats = 8 KB scratch

    yolo_main<<<GRID, BLOCK, 0, stream>>>(pred, label, partials);
    yolo_reduce<<<1, BLOCK, 0, stream>>>(partials, out);
}

// Round 7
// 200.081 us; speedup vs baseline: 1.0559x; 1.0559x over previous
//
#include <hip/hip_runtime.h>

// YOLOv1 loss: pred/label (16384, 30, 7, 7) fp32 -> scalar.
// R6: six structures all pinned at ~2.4 TB/s effective with all pipes idle.
// Split the two halves into SEPARATE dispatches for per-phase attribution:
//   K1: class term (ch10-29, 131 MB) -- pure wave-per-record stream, no
//       divides in loop, weights via __shfl (bpermute), nontemporal float2.
//   K2: box term (ch0-9, 61 MB) -- R5's wave-private LDS gather, full grid.
//   K3: reduce 4096 partials.

typedef float v2f __attribute__((ext_vector_type(2)));

#define NBATCH 16384
#define RECF 1470          // floats per record
#define BLOCK 256
#define GRID 2048
#define NWAVES (GRID * 4)  // 8192 -> 2 records per wave

__device__ __forceinline__ float sq(float x) { return x * x; }

__device__ __forceinline__ float block_reduce(float v, float* smem, int tid) {
#pragma unroll
    for (int off = 32; off > 0; off >>= 1) v += __shfl_down(v, off, 64);
    const int lane = tid & 63, wave = tid >> 6;
    if (lane == 0) smem[wave] = v;
    __syncthreads();
    return smem[0] + smem[1] + smem[2] + smem[3];
}

// ---------------- K1: class term, pure stream ----------------
__global__ __launch_bounds__(BLOCK) void k_class(const float* __restrict__ pred,
                                                 const float* __restrict__ label,
                                                 float* __restrict__ partials) {
    __shared__ float smem[4];
    const int tid = threadIdx.x, lane = tid & 63, wv = tid >> 6;
    const int gw = blockIdx.x * 4 + wv;          // global wave id, 0..8191
    const int c0 = (2 * lane) % 49;              // cell of elem m=2*lane (init only)
    float acc = 0.0f;

    for (int rec = gw; rec < NBATCH; rec += NWAVES) {
        const float* rp = pred + (size_t)rec * RECF;
        const float* rl = label + (size_t)rec * RECF;
        // 49 objectness weights (exactly 0.0/1.0) live in lanes 0..48.
        float w49 = (lane < 49) ? rl[196 + lane] : 0.0f;
        int c = c0;
#pragma unroll
        for (int it = 0; it < 8; ++it) {
            int k = it * 64 + lane;              // float2-pair index in class region
            v2f p2 = {0.0f, 0.0f}, l2 = {0.0f, 0.0f};
            if (k < 490) {
                p2 = __builtin_nontemporal_load((const v2f*)(rp + 490 + 2 * k));
                l2 = __builtin_nontemporal_load((const v2f*)(rl + 490 + 2 * k));
            }
            float w0 = __shfl(w49, c, 64);                 // bpermute, no LDS
            int cn = (c == 48) ? 0 : c + 1;
            float w1 = __shfl(w49, cn, 64);
            float d0 = p2.x - l2.x, d1 = p2.y - l2.y;
            acc += w0 * d0 * d0 + w1 * d1 * d1;
            c += 30; if (c >= 49) c -= 49;       // m += 128; 128 mod 49 = 30
        }
    }

    float s = block_reduce(acc, smem, tid);
    if (tid == 0) partials[blockIdx.x] = s;
}

// ---------------- K2: box term, wave-private LDS gather ----------------
__global__ __launch_bounds__(BLOCK) void k_box(const float* __restrict__ pred,
                                               const float* __restrict__ label,
                                               float* __restrict__ partials) {
    __shared__ float lds[4][960];   // per wave: [0,490) pred ch0-9, [496,937] label ch0-8
    __shared__ float smem[4];
    const int tid = threadIdx.x, lane = tid & 63, wv = tid >> 6;
    const int gw = blockIdx.x * 4 + wv;
    float* ldsw = &lds[wv][0];
    v2f* wp2 = (v2f*)ldsw;          // 245 pairs: pred ch0-9
    v2f* wl2 = (v2f*)(ldsw + 496);  // 221 pairs: label ch0-8 (+1 stray float, unused)

    const int rr = lane / 7, cc = lane - rr * 7;   // valid for lane<49
    const float fr = (float)rr, fcl = (float)cc;
    const float inv7 = 1.0f / 7.0f;
    float acc = 0.0f;

    for (int rec = gw; rec < NBATCH; rec += NWAVES) {
        const v2f* gp = (const v2f*)(pred + (size_t)rec * RECF);
        const v2f* gl = (const v2f*)(label + (size_t)rec * RECF);
#pragma unroll
        for (int r4 = 0; r4 < 4; ++r4) {
            int idx = r4 * 64 + lane;
            if (idx < 245) wp2[idx] = __builtin_nontemporal_load(gp + idx);
            if (idx < 221) wl2[idx] = __builtin_nontemporal_load(gl + idx);
        }
        // Wave-private LDS: drain DS writes; no __syncthreads (waves free-run).
        asm volatile("s_waitcnt lgkmcnt(0)" ::: "memory");

        if (lane < 49) {
            float p[10], l[9];
#pragma unroll
            for (int ch = 0; ch < 10; ++ch) p[ch] = ldsw[ch * 49 + lane];
#pragma unroll
            for (int ch = 0; ch < 9; ++ch) l[ch] = ldsw[496 + ch * 49 + lane];

            float lcx = (l[0] + fcl) * inv7;
            float lcy = (l[1] + fr) * inv7;
            float lhw = l[2] * 0.5f, lhh = l[3] * 0.5f;
            float lx1 = lcx - lhw, ly1 = lcy - lhh;
            float lx2 = lcx + lhw, ly2 = lcy + lhh;
            float larea = (lx2 - lx1) * (ly2 - ly1);

            float cx1 = (p[0] + fcl) * inv7, cy1 = (p[1] + fr) * inv7;
            float x11 = cx1 - p[2] * 0.5f, y11 = cy1 - p[3] * 0.5f;
            float x12 = cx1 + p[2] * 0.5f, y12 = cy1 + p[3] * 0.5f;
            float iw1 = fmaxf(fminf(x12, lx2) - fmaxf(x11, lx1), 0.0f);
            float ih1 = fmaxf(fminf(y12, ly2) - fmaxf(y11, ly1), 0.0f);
            float int1 = iw1 * ih1;
            float a1 = (x12 - x11) * (y12 - y11);
            float iou1 = int1 / (a1 + larea - int1 + 1e-10f);

            float cx2 = (p[5] + fcl) * inv7, cy2 = (p[6] + fr) * inv7;
            float x21 = cx2 - p[7] * 0.5f, y21 = cy2 - p[8] * 0.5f;
            float x22 = cx2 + p[7] * 0.5f, y22 = cy2 + p[8] * 0.5f;
            float iw2 = fmaxf(fminf(x22, lx2) - fmaxf(x21, lx1), 0.0f);
            float ih2 = fmaxf(fminf(y22, ly2) - fmaxf(y21, ly1), 0.0f);
            float int2 = iw2 * ih2;
            float a2 = (x22 - x21) * (y22 - y21);
            float iou2 = int2 / (a2 + larea - int2 + 1e-10f);

            bool ch1 = iou1 >= iou2;

            float coord1 = 5.0f * (sq(p[0] - l[0]) + sq(p[1] - l[1]))
                         + sq(sqrtf(p[2]) - sqrtf(l[2])) + sq(sqrtf(p[3]) - sqrtf(l[3]));
            float coord2 = 5.0f * (sq(p[5] - l[5]) + sq(p[6] - l[6]))
                         + sq(sqrtf(p[7]) - sqrtf(l[7])) + sq(sqrtf(p[8]) - sqrtf(l[8]));
            float obj1 = sq(p[4] - iou1);
            float obj2 = sq(p[9] - iou2);

            float obj_cell = (ch1 ? coord1 : coord2)
                           + (ch1 ? obj1 : obj2)
                           + 0.5f * (ch1 ? obj2 : obj1);   // class term is in K1
            float noobj_cell = 0.5f * sq(p[4] + p[9]);

            acc += (l[4] == 1.0f) ? obj_cell : noobj_cell;
        }
    }

    float s = block_reduce(acc, smem, tid);
    if (tid == 0) partials[blockIdx.x] = s;
}

// ---------------- K3: final reduce ----------------
__global__ __launch_bounds__(BLOCK) void k_reduce(const float* __restrict__ partials,
                                                  float* __restrict__ out) {
    __shared__ float smem[4];
    float s = 0.0f;
#pragma unroll
    for (int it = 0; it < 2 * GRID / BLOCK; ++it)   // 16 independent loads
        s += partials[it * BLOCK + threadIdx.x];
    float t = block_reduce(s, smem, threadIdx.x);
    if (threadIdx.x == 0) out[0] = t * (1.0f / (float)NBATCH);
}

extern "C" void kernel_launch(void* const* d_in, const int* in_sizes, int n_in,
                              void* d_out, int out_size, void* d_ws, size_t ws_size,
                              hipStream_t stream) {
    const float* pred  = (const float*)d_in[0];
    const float* label = (const float*)d_in[1];
    float* out = (float*)d_out;
    float* part1 = (float*)d_ws;          // 2048 floats
    float* part2 = part1 + GRID;          // 2048 floats

    k_class<<<GRID, BLOCK, 0, stream>>>(pred, label, part1);
    k_box<<<GRID, BLOCK, 0, stream>>>(pred, label, part2);
    k_reduce<<<1, BLOCK, 0, stream>>>(part1, out);
}